// Round 4
// baseline (769.084 us; speedup 1.0000x reference)
//
#include <hip/hip_runtime.h>
#include <hip/hip_bf16.h>

#define NN 20000
#define MM 32
#define EE 20
#define HH 128

typedef __attribute__((ext_vector_type(8))) short bf16x8;
typedef __attribute__((ext_vector_type(4))) float f32x4;

// ---------- helpers ----------
__device__ __forceinline__ float bf_lo(unsigned int u) {
    return __uint_as_float(u << 16);
}
__device__ __forceinline__ float bf_hi(unsigned int u) {
    return __uint_as_float(u & 0xFFFF0000u);
}
__device__ __forceinline__ unsigned int pack_bf2(float lo, float hi) {
    unsigned int a = __float_as_uint(lo);
    unsigned int b = __float_as_uint(hi);
    a += 0x7FFFu + ((a >> 16) & 1u);
    b += 0x7FFFu + ((b >> 16) & 1u);
    return (a >> 16) | (b & 0xFFFF0000u);
}
__device__ __forceinline__ unsigned short bf16r(float v) {
    unsigned int u = __float_as_uint(v);
    u += 0x7FFFu + ((u >> 16) & 1u);
    return (unsigned short)(u >> 16);
}
__device__ __forceinline__ float softplusf(float x) {
    return fmaxf(x, 0.f) + __logf(1.f + __expf(-fabsf(x)));
}

// ---------- kernel 1: build Wcat (128 x 1024, pair-encoded cols) ----------
__global__ void build_wcat(const float* __restrict__ cheW,
                           const float* __restrict__ vdwW,
                           float* __restrict__ Wcat) {
    int t = blockIdx.x * 256 + threadIdx.x;   // < 131072
    int k = t >> 10;
    int c = t & 1023;
    int b = c >> 9, sec = (c >> 8) & 1, h = (c >> 1) & 127, slot = c & 1;
    const float* W = b ? vdwW : cheW;
    int row = (sec ? 256 : 0) + k;
    Wcat[t] = W[row * 256 + slot * 128 + h];
}

// ---------- kernel 2: build Bfrag (MFMA B fragments of WfW, bf16) + biasP ----------
// Bfrag element index: (((b*2+w)*8+tc)*64 + l)*8 + i       (2048 fragments)
__global__ void build_bfrag(const float* __restrict__ cheWf, const float* __restrict__ cheBf,
                            const float* __restrict__ cheW,  const float* __restrict__ cheBfull,
                            const float* __restrict__ vdwWf, const float* __restrict__ vdwBf,
                            const float* __restrict__ vdwW,  const float* __restrict__ vdwBfull,
                            unsigned short* __restrict__ Bfrag, float* __restrict__ biasP) {
    int t = blockIdx.x * 256 + threadIdx.x;   // < 2048
    int b = t >> 10, w = (t >> 9) & 1, tc = (t >> 6) & 7, l = t & 63;
    int lhi = l >> 4, llo = l & 15;
    int h = w * 64 + (tc >> 1) * 16 + llo;    // < 128
    int slot = tc & 1;
    int jcol = slot * 128 + h;                // < 256
    const float* Wf = b ? vdwWf : cheWf;
    const float* W  = b ? vdwW  : cheW;

    unsigned short o[8];
#pragma unroll
    for (int i = 0; i < 8; ++i) {
        int k = lhi * 8 + i;
        float a = 0.f;
        if (k < EE)
            for (int h2 = 0; h2 < 128; ++h2)
                a = fmaf(Wf[k * 128 + h2], W[(128 + h2) * 256 + jcol], a);
        o[i] = bf16r(a);
    }
#pragma unroll
    for (int i = 0; i < 8; ++i) Bfrag[t * 8 + i] = o[i];

    if (t < 512) {
        int bb = t >> 8, sl = (t >> 7) & 1, hh = t & 127;
        int jc = sl * 128 + hh;
        const float* bfv   = bb ? vdwBf    : cheBf;
        const float* Wb    = bb ? vdwW     : cheW;
        const float* bfull = bb ? vdwBfull : cheBfull;
        float s = bfull[jc];
        for (int h2 = 0; h2 < 128; ++h2)
            s = fmaf(bfv[h2], Wb[(128 + h2) * 256 + jc], s);
        biasP[t] = s;
    }
}

// ---------- kernel 3: proj GEMM  P[n][512] (bf16x2 packed) = nodes @ Wcat ----------
__global__ __launch_bounds__(256) void proj_kernel(const float* __restrict__ nodes,
                                                   const float* __restrict__ Wcat,
                                                   unsigned int* __restrict__ P) {
    __shared__ float ln[16 * 128];
    int n0 = blockIdx.x * 16;
    int t = threadIdx.x;
    for (int i = t; i < 2048; i += 256) ln[i] = nodes[n0 * 128 + i];
    __syncthreads();

    float4 acc[16];
#pragma unroll
    for (int i = 0; i < 16; ++i) acc[i] = make_float4(0.f, 0.f, 0.f, 0.f);

    int c0 = t * 4;
    for (int k = 0; k < 128; k += 4) {
        float4 w0 = *(const float4*)&Wcat[(k + 0) * 1024 + c0];
        float4 w1 = *(const float4*)&Wcat[(k + 1) * 1024 + c0];
        float4 w2 = *(const float4*)&Wcat[(k + 2) * 1024 + c0];
        float4 w3 = *(const float4*)&Wcat[(k + 3) * 1024 + c0];
#pragma unroll
        for (int ni = 0; ni < 16; ++ni) {
            float4 nv = *(const float4*)&ln[ni * 128 + k];
            acc[ni].x = fmaf(nv.x, w0.x, acc[ni].x);
            acc[ni].y = fmaf(nv.x, w0.y, acc[ni].y);
            acc[ni].z = fmaf(nv.x, w0.z, acc[ni].z);
            acc[ni].w = fmaf(nv.x, w0.w, acc[ni].w);
            acc[ni].x = fmaf(nv.y, w1.x, acc[ni].x);
            acc[ni].y = fmaf(nv.y, w1.y, acc[ni].y);
            acc[ni].z = fmaf(nv.y, w1.z, acc[ni].z);
            acc[ni].w = fmaf(nv.y, w1.w, acc[ni].w);
            acc[ni].x = fmaf(nv.z, w2.x, acc[ni].x);
            acc[ni].y = fmaf(nv.z, w2.y, acc[ni].y);
            acc[ni].z = fmaf(nv.z, w2.z, acc[ni].z);
            acc[ni].w = fmaf(nv.z, w2.w, acc[ni].w);
            acc[ni].x = fmaf(nv.w, w3.x, acc[ni].x);
            acc[ni].y = fmaf(nv.w, w3.y, acc[ni].y);
            acc[ni].z = fmaf(nv.w, w3.z, acc[ni].z);
            acc[ni].w = fmaf(nv.w, w3.w, acc[ni].w);
        }
    }
#pragma unroll
    for (int ni = 0; ni < 16; ++ni) {
        uint2 uu;
        uu.x = pack_bf2(acc[ni].x, acc[ni].y);
        uu.y = pack_bf2(acc[ni].z, acc[ni].w);
        *(uint2*)&P[(n0 + ni) * 512 + t * 2] = uu;
    }
}

// ---------- kernel 4: main — register-lean MFMA + interleaved epilogue ----------
// one block per node, 128 threads = 2 waves; wave w owns h in [w*64, w*64+64)
__global__ __launch_bounds__(128, 6) void main_kernel(
    const float* __restrict__ nodes,
    const float* __restrict__ rbf_che, const int* __restrict__ idx_che,
    const float* __restrict__ rbf_vdw, const int* __restrict__ idx_vdw,
    const unsigned int* __restrict__ P,
    const unsigned short* __restrict__ Bfrag, const float* __restrict__ biasP,
    float* __restrict__ out) {
    // A staging: [b][m][k] bf16, row padded to 40 elems (80 B)
    __shared__ unsigned short sA[2 * 32 * 40];
    __shared__ int sidx[2][MM];
    int n = blockIdx.x;
    int tid = threadIdx.x;
    int w = tid >> 6, l = tid & 63;       // w in {0,1}
    int lhi = l >> 4, llo = l & 15;

    // zero-fill k=20..31 pad (64 rows x 3 uint2)
    for (int i = tid; i < 192; i += 128) {
        int row = i / 3, j = i - row * 3;
        *(uint2*)&sA[row * 40 + 20 + j * 4] = make_uint2(0u, 0u);
    }
    // vectorized rbf staging: 320 float4s (20 floats = 5 float4 per row)
    for (int i = tid; i < 320; i += 128) {
        int b = i / 160, rem = i - b * 160;
        int m = rem / 5, kq = rem - m * 5;
        const float* src = b ? rbf_vdw : rbf_che;
        float4 v = *(const float4*)&src[n * 640 + m * 20 + kq * 4];
        uint2 p;
        p.x = pack_bf2(v.x, v.y);
        p.y = pack_bf2(v.z, v.w);
        *(uint2*)&sA[(b * 32 + m) * 40 + kq * 4] = p;
    }
    if (tid < 64) {
        int b = tid >> 5, m = tid & 31;
        sidx[b][m] = (b ? idx_vdw : idx_che)[n * MM + m];
    }
    __syncthreads();

    float psum0 = 0.f, psum1 = 0.f, psum2 = 0.f, psum3 = 0.f;

#pragma unroll
    for (int b = 0; b < 2; ++b) {
        // A fragments (row = tm*16 + llo, k = lhi*8 + i)
        bf16x8 Af0 = *(const bf16x8*)&sA[(b * 32 + llo) * 40 + lhi * 8];
        bf16x8 Af1 = *(const bf16x8*)&sA[(b * 32 + 16 + llo) * 40 + lhi * 8];
        // neighbor indices for this lane's C/D rows (4 consecutive -> b128)
        int4 vi0 = *(const int4*)&sidx[b][lhi * 4];
        int4 vi1 = *(const int4*)&sidx[b][16 + lhi * 4];
        int vidx0[4] = {vi0.x, vi0.y, vi0.z, vi0.w};
        int vidx1[4] = {vi1.x, vi1.y, vi1.z, vi1.w};

        const unsigned short* bb = Bfrag + (size_t)((b * 2 + w) * 8) * 512;
        const unsigned int* selfP = P + (size_t)n * 512 + b * 256 + w * 64 + llo;
        const float* biasF = biasP + b * 256 + w * 64 + llo;
        size_t gofs = (size_t)(b * 256 + 128 + w * 64 + llo);

#pragma unroll
        for (int tp = 0; tp < 4; ++tp) {
            // B fragments for this c-quadrant (filt tile 2tp, core tile 2tp+1)
            bf16x8 Bf0 = *(const bf16x8*)(bb + ((2 * tp) * 64 + l) * 8);
            bf16x8 Bf1 = *(const bf16x8*)(bb + ((2 * tp + 1) * 64 + l) * 8);

            f32x4 a00 = {0.f, 0.f, 0.f, 0.f}, a01 = {0.f, 0.f, 0.f, 0.f};
            f32x4 a10 = {0.f, 0.f, 0.f, 0.f}, a11 = {0.f, 0.f, 0.f, 0.f};
            a00 = __builtin_amdgcn_mfma_f32_16x16x32_bf16(Af0, Bf0, a00, 0, 0, 0);
            a01 = __builtin_amdgcn_mfma_f32_16x16x32_bf16(Af0, Bf1, a01, 0, 0, 0);
            a10 = __builtin_amdgcn_mfma_f32_16x16x32_bf16(Af1, Bf0, a10, 0, 0, 0);
            a11 = __builtin_amdgcn_mfma_f32_16x16x32_bf16(Af1, Bf1, a11, 0, 0, 0);

            unsigned int su = selfP[tp * 16];
            float baseF = biasF[tp * 16]       + bf_lo(su);
            float baseC = biasF[tp * 16 + 128] + bf_hi(su);
            float ps = 0.f;
#pragma unroll
            for (int r = 0; r < 4; ++r) {
                unsigned int g = P[(size_t)vidx0[r] * 512 + gofs + tp * 16];
                float filt = a00[r] + baseF + bf_lo(g);
                float core = a01[r] + baseC + bf_hi(g);
                float sg = __builtin_amdgcn_rcpf(1.f + __expf(-filt));
                float sp = softplusf(core);
                ps = fmaf(sg, sp, ps);
            }
#pragma unroll
            for (int r = 0; r < 4; ++r) {
                unsigned int g = P[(size_t)vidx1[r] * 512 + gofs + tp * 16];
                float filt = a10[r] + baseF + bf_lo(g);
                float core = a11[r] + baseC + bf_hi(g);
                float sg = __builtin_amdgcn_rcpf(1.f + __expf(-filt));
                float sp = softplusf(core);
                ps = fmaf(sg, sp, ps);
            }
            if (tp == 0) psum0 += ps;
            else if (tp == 1) psum1 += ps;
            else if (tp == 2) psum2 += ps;
            else psum3 += ps;
        }
    }

    // cross-lane reduce over the 4 lhi groups
    float res = 0.f;
    {
        float v = psum0;
        v += __shfl_xor(v, 16);
        v += __shfl_xor(v, 32);
        if (lhi == 0) res = v;
        v = psum1;
        v += __shfl_xor(v, 16);
        v += __shfl_xor(v, 32);
        if (lhi == 1) res = v;
        v = psum2;
        v += __shfl_xor(v, 16);
        v += __shfl_xor(v, 32);
        if (lhi == 2) res = v;
        v = psum3;
        v += __shfl_xor(v, 16);
        v += __shfl_xor(v, 32);
        if (lhi == 3) res = v;
    }
    int h = w * 64 + l;   // < 128
    float x = nodes[n * 128 + h] + res;
    out[n * 128 + h] = softplusf(x);
}

// ---------- launch ----------
extern "C" void kernel_launch(void* const* d_in, const int* in_sizes, int n_in,
                              void* d_out, int out_size, void* d_ws, size_t ws_size,
                              hipStream_t stream) {
    const float* nodes     = (const float*)d_in[0];
    const float* che_rbf   = (const float*)d_in[1];
    const int*   che_idx   = (const int*)d_in[2];
    const float* vdw_rbf   = (const float*)d_in[3];
    const int*   vdw_idx   = (const int*)d_in[4];
    const float* che_Wf    = (const float*)d_in[5];
    const float* che_bf    = (const float*)d_in[6];
    const float* che_Wfull = (const float*)d_in[7];
    const float* che_bfull = (const float*)d_in[8];
    const float* vdw_Wf    = (const float*)d_in[9];
    const float* vdw_bf    = (const float*)d_in[10];
    const float* vdw_Wfull = (const float*)d_in[11];
    const float* vdw_bfull = (const float*)d_in[12];

    char* ws = (char*)d_ws;
    float* Wcat           = (float*)ws;                       // 512 KB
    unsigned short* Bfrag = (unsigned short*)(ws + 524288);   // 32 KB
    float* biasP          = (float*)(ws + 524288 + 32768);    // 2 KB
    unsigned int* P       = (unsigned int*)(ws + 559104);     // 40.96 MB

    build_wcat<<<512, 256, 0, stream>>>(che_Wfull, vdw_Wfull, Wcat);
    build_bfrag<<<8, 256, 0, stream>>>(che_Wf, che_bf, che_Wfull, che_bfull,
                                       vdw_Wf, vdw_bf, vdw_Wfull, vdw_bfull,
                                       Bfrag, biasP);
    proj_kernel<<<NN / 16, 256, 0, stream>>>(nodes, Wcat, P);
    main_kernel<<<NN, 128, 0, stream>>>(nodes, che_rbf, che_idx, vdw_rbf, vdw_idx,
                                        P, Bfrag, biasP, (float*)d_out);
}

// Round 5
// 490.999 us; speedup vs baseline: 1.5664x; 1.5664x over previous
//
#include <hip/hip_runtime.h>
#include <hip/hip_bf16.h>

#define NN 20000
#define MM 32
#define EE 20
#define HH 128

typedef __attribute__((ext_vector_type(8))) short bf16x8;
typedef __attribute__((ext_vector_type(4))) float f32x4;

// ---------- helpers ----------
__device__ __forceinline__ float bf_lo(unsigned int u) {
    return __uint_as_float(u << 16);
}
__device__ __forceinline__ float bf_hi(unsigned int u) {
    return __uint_as_float(u & 0xFFFF0000u);
}
__device__ __forceinline__ unsigned int pack_bf2(float lo, float hi) {
    unsigned int a = __float_as_uint(lo);
    unsigned int b = __float_as_uint(hi);
    a += 0x7FFFu + ((a >> 16) & 1u);
    b += 0x7FFFu + ((b >> 16) & 1u);
    return (a >> 16) | (b & 0xFFFF0000u);
}
__device__ __forceinline__ unsigned short bf16r(float v) {
    unsigned int u = __float_as_uint(v);
    u += 0x7FFFu + ((u >> 16) & 1u);
    return (unsigned short)(u >> 16);
}
__device__ __forceinline__ float softplusf(float x) {
    return fmaxf(x, 0.f) + __logf(1.f + __expf(-fabsf(x)));
}

// ---------- kernel 1: build Wcat (128 x 1024, pair-encoded cols) ----------
__global__ void build_wcat(const float* __restrict__ cheW,
                           const float* __restrict__ vdwW,
                           float* __restrict__ Wcat) {
    int t = blockIdx.x * 256 + threadIdx.x;   // < 131072
    int k = t >> 10;
    int c = t & 1023;
    int b = c >> 9, sec = (c >> 8) & 1, h = (c >> 1) & 127, slot = c & 1;
    const float* W = b ? vdwW : cheW;
    int row = (sec ? 256 : 0) + k;
    Wcat[t] = W[row * 256 + slot * 128 + h];
}

// ---------- kernel 2: build Bfrag (MFMA B fragments of WfW, bf16) + biasP ----------
// Bfrag element index: (((b*2+w)*8+tc)*64 + l)*8 + i       (2048 fragments)
__global__ void build_bfrag(const float* __restrict__ cheWf, const float* __restrict__ cheBf,
                            const float* __restrict__ cheW,  const float* __restrict__ cheBfull,
                            const float* __restrict__ vdwWf, const float* __restrict__ vdwBf,
                            const float* __restrict__ vdwW,  const float* __restrict__ vdwBfull,
                            unsigned short* __restrict__ Bfrag, float* __restrict__ biasP) {
    int t = blockIdx.x * 256 + threadIdx.x;   // < 2048
    int b = t >> 10, w = (t >> 9) & 1, tc = (t >> 6) & 7, l = t & 63;
    int lhi = l >> 4, llo = l & 15;
    int h = w * 64 + (tc >> 1) * 16 + llo;    // < 128
    int slot = tc & 1;
    int jcol = slot * 128 + h;                // < 256
    const float* Wf = b ? vdwWf : cheWf;
    const float* W  = b ? vdwW  : cheW;

    unsigned short o[8];
#pragma unroll
    for (int i = 0; i < 8; ++i) {
        int k = lhi * 8 + i;
        float a = 0.f;
        if (k < EE)
            for (int h2 = 0; h2 < 128; ++h2)
                a = fmaf(Wf[k * 128 + h2], W[(128 + h2) * 256 + jcol], a);
        o[i] = bf16r(a);
    }
#pragma unroll
    for (int i = 0; i < 8; ++i) Bfrag[t * 8 + i] = o[i];

    if (t < 512) {
        int bb = t >> 8, sl = (t >> 7) & 1, hh = t & 127;
        int jc = sl * 128 + hh;
        const float* bfv   = bb ? vdwBf    : cheBf;
        const float* Wb    = bb ? vdwW     : cheW;
        const float* bfull = bb ? vdwBfull : cheBfull;
        float s = bfull[jc];
        for (int h2 = 0; h2 < 128; ++h2)
            s = fmaf(bfv[h2], Wb[(128 + h2) * 256 + jc], s);
        biasP[t] = s;
    }
}

// ---------- kernel 3: proj GEMM  P[n][512] (bf16x2 packed) = nodes @ Wcat ----------
__global__ __launch_bounds__(256) void proj_kernel(const float* __restrict__ nodes,
                                                   const float* __restrict__ Wcat,
                                                   unsigned int* __restrict__ P) {
    __shared__ float ln[16 * 128];
    int n0 = blockIdx.x * 16;
    int t = threadIdx.x;
    for (int i = t; i < 2048; i += 256) ln[i] = nodes[n0 * 128 + i];
    __syncthreads();

    float4 acc[16];
#pragma unroll
    for (int i = 0; i < 16; ++i) acc[i] = make_float4(0.f, 0.f, 0.f, 0.f);

    int c0 = t * 4;
    for (int k = 0; k < 128; k += 4) {
        float4 w0 = *(const float4*)&Wcat[(k + 0) * 1024 + c0];
        float4 w1 = *(const float4*)&Wcat[(k + 1) * 1024 + c0];
        float4 w2 = *(const float4*)&Wcat[(k + 2) * 1024 + c0];
        float4 w3 = *(const float4*)&Wcat[(k + 3) * 1024 + c0];
#pragma unroll
        for (int ni = 0; ni < 16; ++ni) {
            float4 nv = *(const float4*)&ln[ni * 128 + k];
            acc[ni].x = fmaf(nv.x, w0.x, acc[ni].x);
            acc[ni].y = fmaf(nv.x, w0.y, acc[ni].y);
            acc[ni].z = fmaf(nv.x, w0.z, acc[ni].z);
            acc[ni].w = fmaf(nv.x, w0.w, acc[ni].w);
            acc[ni].x = fmaf(nv.y, w1.x, acc[ni].x);
            acc[ni].y = fmaf(nv.y, w1.y, acc[ni].y);
            acc[ni].z = fmaf(nv.y, w1.z, acc[ni].z);
            acc[ni].w = fmaf(nv.y, w1.w, acc[ni].w);
            acc[ni].x = fmaf(nv.z, w2.x, acc[ni].x);
            acc[ni].y = fmaf(nv.z, w2.y, acc[ni].y);
            acc[ni].z = fmaf(nv.z, w2.z, acc[ni].z);
            acc[ni].w = fmaf(nv.z, w2.w, acc[ni].w);
            acc[ni].x = fmaf(nv.w, w3.x, acc[ni].x);
            acc[ni].y = fmaf(nv.w, w3.y, acc[ni].y);
            acc[ni].z = fmaf(nv.w, w3.z, acc[ni].z);
            acc[ni].w = fmaf(nv.w, w3.w, acc[ni].w);
        }
    }
#pragma unroll
    for (int ni = 0; ni < 16; ++ni) {
        uint2 uu;
        uu.x = pack_bf2(acc[ni].x, acc[ni].y);
        uu.y = pack_bf2(acc[ni].z, acc[ni].w);
        *(uint2*)&P[(n0 + ni) * 512 + t * 2] = uu;
    }
}

// ---------- kernel 4: main — register-lean MFMA + interleaved epilogue ----------
// one block per node, 128 threads = 2 waves; wave w owns h in [w*64, w*64+64)
// launch_bounds(128,4): 128-reg budget — fits the ~80-reg live set WITHOUT
// spilling (R4's (128,6)=85-reg cap spilled: WRITE_SIZE 10MB->1.36GB).
__global__ __launch_bounds__(128, 4) void main_kernel(
    const float* __restrict__ nodes,
    const float* __restrict__ rbf_che, const int* __restrict__ idx_che,
    const float* __restrict__ rbf_vdw, const int* __restrict__ idx_vdw,
    const unsigned int* __restrict__ P,
    const unsigned short* __restrict__ Bfrag, const float* __restrict__ biasP,
    float* __restrict__ out) {
    // A staging: [b][m][k] bf16, row padded to 40 elems (80 B)
    __shared__ unsigned short sA[2 * 32 * 40];
    __shared__ int sidx[2][MM];
    int n = blockIdx.x;
    int tid = threadIdx.x;
    int w = tid >> 6, l = tid & 63;       // w in {0,1}
    int lhi = l >> 4, llo = l & 15;

    // zero-fill k=20..31 pad (64 rows x 3 uint2)
    for (int i = tid; i < 192; i += 128) {
        int row = i / 3, j = i - row * 3;
        *(uint2*)&sA[row * 40 + 20 + j * 4] = make_uint2(0u, 0u);
    }
    // vectorized rbf staging: 320 float4s (20 floats = 5 float4 per row)
    for (int i = tid; i < 320; i += 128) {
        int b = i / 160, rem = i - b * 160;
        int m = rem / 5, kq = rem - m * 5;
        const float* src = b ? rbf_vdw : rbf_che;
        float4 v = *(const float4*)&src[n * 640 + m * 20 + kq * 4];
        uint2 p;
        p.x = pack_bf2(v.x, v.y);
        p.y = pack_bf2(v.z, v.w);
        *(uint2*)&sA[(b * 32 + m) * 40 + kq * 4] = p;
    }
    if (tid < 64) {
        int b = tid >> 5, m = tid & 31;
        sidx[b][m] = (b ? idx_vdw : idx_che)[n * MM + m];
    }
    __syncthreads();

    float psum0 = 0.f, psum1 = 0.f, psum2 = 0.f, psum3 = 0.f;

#pragma unroll
    for (int b = 0; b < 2; ++b) {
        // A fragments (row = tm*16 + llo, k = lhi*8 + i)
        bf16x8 Af0 = *(const bf16x8*)&sA[(b * 32 + llo) * 40 + lhi * 8];
        bf16x8 Af1 = *(const bf16x8*)&sA[(b * 32 + 16 + llo) * 40 + lhi * 8];
        // neighbor indices for this lane's C/D rows (4 consecutive -> b128)
        int4 vi0 = *(const int4*)&sidx[b][lhi * 4];
        int4 vi1 = *(const int4*)&sidx[b][16 + lhi * 4];
        int vidx0[4] = {vi0.x, vi0.y, vi0.z, vi0.w};
        int vidx1[4] = {vi1.x, vi1.y, vi1.z, vi1.w};

        const unsigned short* bb = Bfrag + (size_t)((b * 2 + w) * 8) * 512;
        const unsigned int* selfP = P + (size_t)n * 512 + b * 256 + w * 64 + llo;
        const float* biasF = biasP + b * 256 + w * 64 + llo;
        size_t gofs = (size_t)(b * 256 + 128 + w * 64 + llo);

#pragma unroll
        for (int tp = 0; tp < 4; ++tp) {
            // B fragments for this c-quadrant (filt tile 2tp, core tile 2tp+1)
            bf16x8 Bf0 = *(const bf16x8*)(bb + ((2 * tp) * 64 + l) * 8);
            bf16x8 Bf1 = *(const bf16x8*)(bb + ((2 * tp + 1) * 64 + l) * 8);

            f32x4 a00 = {0.f, 0.f, 0.f, 0.f}, a01 = {0.f, 0.f, 0.f, 0.f};
            f32x4 a10 = {0.f, 0.f, 0.f, 0.f}, a11 = {0.f, 0.f, 0.f, 0.f};
            a00 = __builtin_amdgcn_mfma_f32_16x16x32_bf16(Af0, Bf0, a00, 0, 0, 0);
            a01 = __builtin_amdgcn_mfma_f32_16x16x32_bf16(Af0, Bf1, a01, 0, 0, 0);
            a10 = __builtin_amdgcn_mfma_f32_16x16x32_bf16(Af1, Bf0, a10, 0, 0, 0);
            a11 = __builtin_amdgcn_mfma_f32_16x16x32_bf16(Af1, Bf1, a11, 0, 0, 0);

            unsigned int su = selfP[tp * 16];
            float baseF = biasF[tp * 16]       + bf_lo(su);
            float baseC = biasF[tp * 16 + 128] + bf_hi(su);
            float ps = 0.f;
#pragma unroll
            for (int r = 0; r < 4; ++r) {
                unsigned int g = P[(size_t)vidx0[r] * 512 + gofs + tp * 16];
                float filt = a00[r] + baseF + bf_lo(g);
                float core = a01[r] + baseC + bf_hi(g);
                float sg = __builtin_amdgcn_rcpf(1.f + __expf(-filt));
                float sp = softplusf(core);
                ps = fmaf(sg, sp, ps);
            }
#pragma unroll
            for (int r = 0; r < 4; ++r) {
                unsigned int g = P[(size_t)vidx1[r] * 512 + gofs + tp * 16];
                float filt = a10[r] + baseF + bf_lo(g);
                float core = a11[r] + baseC + bf_hi(g);
                float sg = __builtin_amdgcn_rcpf(1.f + __expf(-filt));
                float sp = softplusf(core);
                ps = fmaf(sg, sp, ps);
            }
            if (tp == 0) psum0 += ps;
            else if (tp == 1) psum1 += ps;
            else if (tp == 2) psum2 += ps;
            else psum3 += ps;
        }
    }

    // cross-lane reduce over the 4 lhi groups
    float res = 0.f;
    {
        float v = psum0;
        v += __shfl_xor(v, 16);
        v += __shfl_xor(v, 32);
        if (lhi == 0) res = v;
        v = psum1;
        v += __shfl_xor(v, 16);
        v += __shfl_xor(v, 32);
        if (lhi == 1) res = v;
        v = psum2;
        v += __shfl_xor(v, 16);
        v += __shfl_xor(v, 32);
        if (lhi == 2) res = v;
        v = psum3;
        v += __shfl_xor(v, 16);
        v += __shfl_xor(v, 32);
        if (lhi == 3) res = v;
    }
    int h = w * 64 + l;   // < 128
    float x = nodes[n * 128 + h] + res;
    out[n * 128 + h] = softplusf(x);
}

// ---------- launch ----------
extern "C" void kernel_launch(void* const* d_in, const int* in_sizes, int n_in,
                              void* d_out, int out_size, void* d_ws, size_t ws_size,
                              hipStream_t stream) {
    const float* nodes     = (const float*)d_in[0];
    const float* che_rbf   = (const float*)d_in[1];
    const int*   che_idx   = (const int*)d_in[2];
    const float* vdw_rbf   = (const float*)d_in[3];
    const int*   vdw_idx   = (const int*)d_in[4];
    const float* che_Wf    = (const float*)d_in[5];
    const float* che_bf    = (const float*)d_in[6];
    const float* che_Wfull = (const float*)d_in[7];
    const float* che_bfull = (const float*)d_in[8];
    const float* vdw_Wf    = (const float*)d_in[9];
    const float* vdw_bf    = (const float*)d_in[10];
    const float* vdw_Wfull = (const float*)d_in[11];
    const float* vdw_bfull = (const float*)d_in[12];

    char* ws = (char*)d_ws;
    float* Wcat           = (float*)ws;                       // 512 KB
    unsigned short* Bfrag = (unsigned short*)(ws + 524288);   // 32 KB
    float* biasP          = (float*)(ws + 524288 + 32768);    // 2 KB
    unsigned int* P       = (unsigned int*)(ws + 559104);     // 40.96 MB

    build_wcat<<<512, 256, 0, stream>>>(che_Wfull, vdw_Wfull, Wcat);
    build_bfrag<<<8, 256, 0, stream>>>(che_Wf, che_bf, che_Wfull, che_bfull,
                                       vdw_Wf, vdw_bf, vdw_Wfull, vdw_bfull,
                                       Bfrag, biasP);
    proj_kernel<<<NN / 16, 256, 0, stream>>>(nodes, Wcat, P);
    main_kernel<<<NN, 128, 0, stream>>>(nodes, che_rbf, che_idx, vdw_rbf, vdw_idx,
                                        P, Bfrag, biasP, (float*)d_out);
}

// Round 6
// 340.669 us; speedup vs baseline: 2.2576x; 1.4413x over previous
//
#include <hip/hip_runtime.h>
#include <hip/hip_bf16.h>

#define NN 20000
#define MM 32
#define EE 20
#define HH 128

typedef __attribute__((ext_vector_type(8))) short bf16x8;
typedef __attribute__((ext_vector_type(4))) float f32x4;

// ---------- helpers ----------
__device__ __forceinline__ float bf_lo(unsigned int u) {
    return __uint_as_float(u << 16);
}
__device__ __forceinline__ float bf_hi(unsigned int u) {
    return __uint_as_float(u & 0xFFFF0000u);
}
__device__ __forceinline__ unsigned int pack_bf2(float lo, float hi) {
    unsigned int a = __float_as_uint(lo);
    unsigned int b = __float_as_uint(hi);
    a += 0x7FFFu + ((a >> 16) & 1u);
    b += 0x7FFFu + ((b >> 16) & 1u);
    return (a >> 16) | (b & 0xFFFF0000u);
}
__device__ __forceinline__ unsigned short bf16r(float v) {
    unsigned int u = __float_as_uint(v);
    u += 0x7FFFu + ((u >> 16) & 1u);
    return (unsigned short)(u >> 16);
}
__device__ __forceinline__ float softplusf(float x) {
    return fmaxf(x, 0.f) + __logf(1.f + __expf(-fabsf(x)));
}

// ---------- kernel 1: build Wcat (128 x 1024, pair-encoded cols) ----------
__global__ void build_wcat(const float* __restrict__ cheW,
                           const float* __restrict__ vdwW,
                           float* __restrict__ Wcat) {
    int t = blockIdx.x * 256 + threadIdx.x;   // < 131072
    int k = t >> 10;
    int c = t & 1023;
    int b = c >> 9, sec = (c >> 8) & 1, h = (c >> 1) & 127, slot = c & 1;
    const float* W = b ? vdwW : cheW;
    int row = (sec ? 256 : 0) + k;
    Wcat[t] = W[row * 256 + slot * 128 + h];
}

// ---------- kernel 2: build Bfrag (MFMA B fragments of WfW, bf16) + biasP ----------
// Bfrag element index: (((b*2+w)*8+tc)*64 + l)*8 + i       (2048 fragments)
__global__ void build_bfrag(const float* __restrict__ cheWf, const float* __restrict__ cheBf,
                            const float* __restrict__ cheW,  const float* __restrict__ cheBfull,
                            const float* __restrict__ vdwWf, const float* __restrict__ vdwBf,
                            const float* __restrict__ vdwW,  const float* __restrict__ vdwBfull,
                            unsigned short* __restrict__ Bfrag, float* __restrict__ biasP) {
    int t = blockIdx.x * 256 + threadIdx.x;   // < 2048
    int b = t >> 10, w = (t >> 9) & 1, tc = (t >> 6) & 7, l = t & 63;
    int lhi = l >> 4, llo = l & 15;
    int h = w * 64 + (tc >> 1) * 16 + llo;    // < 128
    int slot = tc & 1;
    int jcol = slot * 128 + h;                // < 256
    const float* Wf = b ? vdwWf : cheWf;
    const float* W  = b ? vdwW  : cheW;

    unsigned short o[8];
#pragma unroll
    for (int i = 0; i < 8; ++i) {
        int k = lhi * 8 + i;
        float a = 0.f;
        if (k < EE)
            for (int h2 = 0; h2 < 128; ++h2)
                a = fmaf(Wf[k * 128 + h2], W[(128 + h2) * 256 + jcol], a);
        o[i] = bf16r(a);
    }
#pragma unroll
    for (int i = 0; i < 8; ++i) Bfrag[t * 8 + i] = o[i];

    if (t < 512) {
        int bb = t >> 8, sl = (t >> 7) & 1, hh = t & 127;
        int jc = sl * 128 + hh;
        const float* bfv   = bb ? vdwBf    : cheBf;
        const float* Wb    = bb ? vdwW     : cheW;
        const float* bfull = bb ? vdwBfull : cheBfull;
        float s = bfull[jc];
        for (int h2 = 0; h2 < 128; ++h2)
            s = fmaf(bfv[h2], Wb[(128 + h2) * 256 + jc], s);
        biasP[t] = s;
    }
}

// ---------- kernel 3: proj GEMM  P[n][512] (bf16x2 packed) = nodes @ Wcat ----------
__global__ __launch_bounds__(256) void proj_kernel(const float* __restrict__ nodes,
                                                   const float* __restrict__ Wcat,
                                                   unsigned int* __restrict__ P) {
    __shared__ float ln[16 * 128];
    int n0 = blockIdx.x * 16;
    int t = threadIdx.x;
    for (int i = t; i < 2048; i += 256) ln[i] = nodes[n0 * 128 + i];
    __syncthreads();

    float4 acc[16];
#pragma unroll
    for (int i = 0; i < 16; ++i) acc[i] = make_float4(0.f, 0.f, 0.f, 0.f);

    int c0 = t * 4;
    for (int k = 0; k < 128; k += 4) {
        float4 w0 = *(const float4*)&Wcat[(k + 0) * 1024 + c0];
        float4 w1 = *(const float4*)&Wcat[(k + 1) * 1024 + c0];
        float4 w2 = *(const float4*)&Wcat[(k + 2) * 1024 + c0];
        float4 w3 = *(const float4*)&Wcat[(k + 3) * 1024 + c0];
#pragma unroll
        for (int ni = 0; ni < 16; ++ni) {
            float4 nv = *(const float4*)&ln[ni * 128 + k];
            acc[ni].x = fmaf(nv.x, w0.x, acc[ni].x);
            acc[ni].y = fmaf(nv.x, w0.y, acc[ni].y);
            acc[ni].z = fmaf(nv.x, w0.z, acc[ni].z);
            acc[ni].w = fmaf(nv.x, w0.w, acc[ni].w);
            acc[ni].x = fmaf(nv.y, w1.x, acc[ni].x);
            acc[ni].y = fmaf(nv.y, w1.y, acc[ni].y);
            acc[ni].z = fmaf(nv.y, w1.z, acc[ni].z);
            acc[ni].w = fmaf(nv.y, w1.w, acc[ni].w);
            acc[ni].x = fmaf(nv.z, w2.x, acc[ni].x);
            acc[ni].y = fmaf(nv.z, w2.y, acc[ni].y);
            acc[ni].z = fmaf(nv.z, w2.z, acc[ni].z);
            acc[ni].w = fmaf(nv.z, w2.w, acc[ni].w);
            acc[ni].x = fmaf(nv.w, w3.x, acc[ni].x);
            acc[ni].y = fmaf(nv.w, w3.y, acc[ni].y);
            acc[ni].z = fmaf(nv.w, w3.z, acc[ni].z);
            acc[ni].w = fmaf(nv.w, w3.w, acc[ni].w);
        }
    }
#pragma unroll
    for (int ni = 0; ni < 16; ++ni) {
        uint2 uu;
        uu.x = pack_bf2(acc[ni].x, acc[ni].y);
        uu.y = pack_bf2(acc[ni].z, acc[ni].w);
        *(uint2*)&P[(n0 + ni) * 512 + t * 2] = uu;
    }
}

// ---------- kernel 4: main — per-quadrant MFMA + epilogue, sched-fenced ----------
// one block per node, 128 threads = 2 waves; wave w owns h in [w*64, w*64+64)
// NO min-waves launch bound (R4/R5: any forced cap -> scratch spill, 500MB+
// round-trip). Pressure is contained by sched_barrier(0) fences at quadrant
// boundaries, which stop cross-quadrant hoisting of B-frag loads / gathers.
__global__ __launch_bounds__(128) void main_kernel(
    const float* __restrict__ nodes,
    const float* __restrict__ rbf_che, const int* __restrict__ idx_che,
    const float* __restrict__ rbf_vdw, const int* __restrict__ idx_vdw,
    const unsigned int* __restrict__ P,
    const unsigned short* __restrict__ Bfrag, const float* __restrict__ biasP,
    float* __restrict__ out) {
    // A staging: [b][m][k] bf16, row padded to 40 elems (80 B)
    __shared__ unsigned short sA[2 * 32 * 40];
    __shared__ int sidx[2][MM];
    int n = blockIdx.x;
    int tid = threadIdx.x;
    int w = tid >> 6, l = tid & 63;       // w in {0,1}
    int lhi = l >> 4, llo = l & 15;

    // zero-fill k=20..31 pad (64 rows x 3 uint2)
    for (int i = tid; i < 192; i += 128) {
        int row = i / 3, j = i - row * 3;
        *(uint2*)&sA[row * 40 + 20 + j * 4] = make_uint2(0u, 0u);
    }
    // vectorized rbf staging: 320 float4s (20 floats = 5 float4 per row)
    for (int i = tid; i < 320; i += 128) {
        int b = i / 160, rem = i - b * 160;
        int m = rem / 5, kq = rem - m * 5;
        const float* src = b ? rbf_vdw : rbf_che;
        float4 v = *(const float4*)&src[n * 640 + m * 20 + kq * 4];
        uint2 p;
        p.x = pack_bf2(v.x, v.y);
        p.y = pack_bf2(v.z, v.w);
        *(uint2*)&sA[(b * 32 + m) * 40 + kq * 4] = p;
    }
    if (tid < 64) {
        int b = tid >> 5, m = tid & 31;
        sidx[b][m] = (b ? idx_vdw : idx_che)[n * MM + m];
    }
    __syncthreads();

    float psum0 = 0.f, psum1 = 0.f, psum2 = 0.f, psum3 = 0.f;

#pragma unroll
    for (int b = 0; b < 2; ++b) {
        // A fragments (row = tm*16 + llo, k = lhi*8 + i)
        bf16x8 Af0 = *(const bf16x8*)&sA[(b * 32 + llo) * 40 + lhi * 8];
        bf16x8 Af1 = *(const bf16x8*)&sA[(b * 32 + 16 + llo) * 40 + lhi * 8];
        // neighbor indices for this lane's C/D rows (4 consecutive -> b128)
        int4 vi0 = *(const int4*)&sidx[b][lhi * 4];
        int4 vi1 = *(const int4*)&sidx[b][16 + lhi * 4];
        int vidx0[4] = {vi0.x, vi0.y, vi0.z, vi0.w};
        int vidx1[4] = {vi1.x, vi1.y, vi1.z, vi1.w};

        const unsigned short* bb = Bfrag + (size_t)((b * 2 + w) * 8) * 512;
        const unsigned int* selfP = P + (size_t)n * 512 + b * 256 + w * 64 + llo;
        const float* biasF = biasP + b * 256 + w * 64 + llo;
        size_t gofs = (size_t)(b * 256 + 128 + w * 64 + llo);

#pragma unroll
        for (int tp = 0; tp < 4; ++tp) {
            // B fragments for this c-quadrant (filt tile 2tp, core tile 2tp+1)
            bf16x8 Bf0 = *(const bf16x8*)(bb + ((2 * tp) * 64 + l) * 8);
            bf16x8 Bf1 = *(const bf16x8*)(bb + ((2 * tp + 1) * 64 + l) * 8);

            f32x4 a00 = {0.f, 0.f, 0.f, 0.f}, a01 = {0.f, 0.f, 0.f, 0.f};
            f32x4 a10 = {0.f, 0.f, 0.f, 0.f}, a11 = {0.f, 0.f, 0.f, 0.f};
            a00 = __builtin_amdgcn_mfma_f32_16x16x32_bf16(Af0, Bf0, a00, 0, 0, 0);
            a01 = __builtin_amdgcn_mfma_f32_16x16x32_bf16(Af0, Bf1, a01, 0, 0, 0);
            a10 = __builtin_amdgcn_mfma_f32_16x16x32_bf16(Af1, Bf0, a10, 0, 0, 0);
            a11 = __builtin_amdgcn_mfma_f32_16x16x32_bf16(Af1, Bf1, a11, 0, 0, 0);

            unsigned int su = selfP[tp * 16];
            float baseF = biasF[tp * 16]       + bf_lo(su);
            float baseC = biasF[tp * 16 + 128] + bf_hi(su);
            float ps = 0.f;
#pragma unroll
            for (int r = 0; r < 4; ++r) {
                unsigned int g = P[(size_t)vidx0[r] * 512 + gofs + tp * 16];
                float filt = a00[r] + baseF + bf_lo(g);
                float core = a01[r] + baseC + bf_hi(g);
                float sg = __builtin_amdgcn_rcpf(1.f + __expf(-filt));
                float sp = softplusf(core);
                ps = fmaf(sg, sp, ps);
            }
#pragma unroll
            for (int r = 0; r < 4; ++r) {
                unsigned int g = P[(size_t)vidx1[r] * 512 + gofs + tp * 16];
                float filt = a10[r] + baseF + bf_lo(g);
                float core = a11[r] + baseC + bf_hi(g);
                float sg = __builtin_amdgcn_rcpf(1.f + __expf(-filt));
                float sp = softplusf(core);
                ps = fmaf(sg, sp, ps);
            }
            if (tp == 0) psum0 += ps;
            else if (tp == 1) psum1 += ps;
            else if (tp == 2) psum2 += ps;
            else psum3 += ps;

            // fence: keep next quadrant's loads from hoisting into this one
            // (pressure control, not pipeline pinning — regions are ~100 insts)
            __builtin_amdgcn_sched_barrier(0);
        }
    }

    // cross-lane reduce over the 4 lhi groups
    float res = 0.f;
    {
        float v = psum0;
        v += __shfl_xor(v, 16);
        v += __shfl_xor(v, 32);
        if (lhi == 0) res = v;
        v = psum1;
        v += __shfl_xor(v, 16);
        v += __shfl_xor(v, 32);
        if (lhi == 1) res = v;
        v = psum2;
        v += __shfl_xor(v, 16);
        v += __shfl_xor(v, 32);
        if (lhi == 2) res = v;
        v = psum3;
        v += __shfl_xor(v, 16);
        v += __shfl_xor(v, 32);
        if (lhi == 3) res = v;
    }
    int h = w * 64 + l;   // < 128
    float x = nodes[n * 128 + h] + res;
    out[n * 128 + h] = softplusf(x);
}

// ---------- launch ----------
extern "C" void kernel_launch(void* const* d_in, const int* in_sizes, int n_in,
                              void* d_out, int out_size, void* d_ws, size_t ws_size,
                              hipStream_t stream) {
    const float* nodes     = (const float*)d_in[0];
    const float* che_rbf   = (const float*)d_in[1];
    const int*   che_idx   = (const int*)d_in[2];
    const float* vdw_rbf   = (const float*)d_in[3];
    const int*   vdw_idx   = (const int*)d_in[4];
    const float* che_Wf    = (const float*)d_in[5];
    const float* che_bf    = (const float*)d_in[6];
    const float* che_Wfull = (const float*)d_in[7];
    const float* che_bfull = (const float*)d_in[8];
    const float* vdw_Wf    = (const float*)d_in[9];
    const float* vdw_bf    = (const float*)d_in[10];
    const float* vdw_Wfull = (const float*)d_in[11];
    const float* vdw_bfull = (const float*)d_in[12];

    char* ws = (char*)d_ws;
    float* Wcat           = (float*)ws;                       // 512 KB
    unsigned short* Bfrag = (unsigned short*)(ws + 524288);   // 32 KB
    float* biasP          = (float*)(ws + 524288 + 32768);    // 2 KB
    unsigned int* P       = (unsigned int*)(ws + 559104);     // 40.96 MB

    build_wcat<<<512, 256, 0, stream>>>(che_Wfull, vdw_Wfull, Wcat);
    build_bfrag<<<8, 256, 0, stream>>>(che_Wf, che_bf, che_Wfull, che_bfull,
                                       vdw_Wf, vdw_bf, vdw_Wfull, vdw_bfull,
                                       Bfrag, biasP);
    proj_kernel<<<NN / 16, 256, 0, stream>>>(nodes, Wcat, P);
    main_kernel<<<NN, 128, 0, stream>>>(nodes, che_rbf, che_idx, vdw_rbf, vdw_idx,
                                        P, Bfrag, biasP, (float*)d_out);
}

// Round 7
// 271.276 us; speedup vs baseline: 2.8351x; 1.2558x over previous
//
#include <hip/hip_runtime.h>
#include <hip/hip_bf16.h>

#define NN 20000
#define MM 32
#define EE 20
#define HH 128

typedef __attribute__((ext_vector_type(8))) short bf16x8;
typedef __attribute__((ext_vector_type(4))) float f32x4;

// ---------- helpers ----------
__device__ __forceinline__ float bf_lo(unsigned int u) {
    return __uint_as_float(u << 16);
}
__device__ __forceinline__ float bf_hi(unsigned int u) {
    return __uint_as_float(u & 0xFFFF0000u);
}
__device__ __forceinline__ unsigned int pack_bf2(float lo, float hi) {
    unsigned int a = __float_as_uint(lo);
    unsigned int b = __float_as_uint(hi);
    a += 0x7FFFu + ((a >> 16) & 1u);
    b += 0x7FFFu + ((b >> 16) & 1u);
    return (a >> 16) | (b & 0xFFFF0000u);
}
__device__ __forceinline__ unsigned short bf16r(float v) {
    unsigned int u = __float_as_uint(v);
    u += 0x7FFFu + ((u >> 16) & 1u);
    return (unsigned short)(u >> 16);
}
__device__ __forceinline__ float softplusf(float x) {
    return fmaxf(x, 0.f) + __logf(1.f + __expf(-fabsf(x)));
}

// ---------- kernel 1: build Wcat (128 x 1024, pair-encoded cols) ----------
__global__ void build_wcat(const float* __restrict__ cheW,
                           const float* __restrict__ vdwW,
                           float* __restrict__ Wcat) {
    int t = blockIdx.x * 256 + threadIdx.x;   // < 131072
    int k = t >> 10;
    int c = t & 1023;
    int b = c >> 9, sec = (c >> 8) & 1, h = (c >> 1) & 127, slot = c & 1;
    const float* W = b ? vdwW : cheW;
    int row = (sec ? 256 : 0) + k;
    Wcat[t] = W[row * 256 + slot * 128 + h];
}

// ---------- kernel 2: build Bfrag (MFMA B fragments of WfW, bf16) + biasP ----------
// Bfrag element index: (((b*2+wold)*8+tc)*64 + l)*8 + i   (2048 fragments)
//   wold in {0,1} covers h in [wold*64, wold*64+64); tile tc: h = wold*64 + (tc>>1)*16 + (l&15),
//   slot = tc&1, jcol = slot*128 + h; k = (l>>4)*8 + i (pad k>=20 with 0).
__global__ void build_bfrag(const float* __restrict__ cheWf, const float* __restrict__ cheBf,
                            const float* __restrict__ cheW,  const float* __restrict__ cheBfull,
                            const float* __restrict__ vdwWf, const float* __restrict__ vdwBf,
                            const float* __restrict__ vdwW,  const float* __restrict__ vdwBfull,
                            unsigned short* __restrict__ Bfrag, float* __restrict__ biasP) {
    int t = blockIdx.x * 256 + threadIdx.x;   // < 2048
    int b = t >> 10, w = (t >> 9) & 1, tc = (t >> 6) & 7, l = t & 63;
    int lhi = l >> 4, llo = l & 15;
    int h = w * 64 + (tc >> 1) * 16 + llo;    // < 128
    int slot = tc & 1;
    int jcol = slot * 128 + h;                // < 256
    const float* Wf = b ? vdwWf : cheWf;
    const float* W  = b ? vdwW  : cheW;

    unsigned short o[8];
#pragma unroll
    for (int i = 0; i < 8; ++i) {
        int k = lhi * 8 + i;
        float a = 0.f;
        if (k < EE)
            for (int h2 = 0; h2 < 128; ++h2)
                a = fmaf(Wf[k * 128 + h2], W[(128 + h2) * 256 + jcol], a);
        o[i] = bf16r(a);
    }
#pragma unroll
    for (int i = 0; i < 8; ++i) Bfrag[t * 8 + i] = o[i];

    if (t < 512) {
        int bb = t >> 8, sl = (t >> 7) & 1, hh = t & 127;
        int jc = sl * 128 + hh;
        const float* bfv   = bb ? vdwBf    : cheBf;
        const float* Wb    = bb ? vdwW     : cheW;
        const float* bfull = bb ? vdwBfull : cheBfull;
        float s = bfull[jc];
        for (int h2 = 0; h2 < 128; ++h2)
            s = fmaf(bfv[h2], Wb[(128 + h2) * 256 + jc], s);
        biasP[t] = s;
    }
}

// ---------- kernel 3: proj GEMM  P[n][512] (bf16x2 packed) = nodes @ Wcat ----------
__global__ __launch_bounds__(256) void proj_kernel(const float* __restrict__ nodes,
                                                   const float* __restrict__ Wcat,
                                                   unsigned int* __restrict__ P) {
    __shared__ float ln[16 * 128];
    int n0 = blockIdx.x * 16;
    int t = threadIdx.x;
    for (int i = t; i < 2048; i += 256) ln[i] = nodes[n0 * 128 + i];
    __syncthreads();

    float4 acc[16];
#pragma unroll
    for (int i = 0; i < 16; ++i) acc[i] = make_float4(0.f, 0.f, 0.f, 0.f);

    int c0 = t * 4;
    for (int k = 0; k < 128; k += 4) {
        float4 w0 = *(const float4*)&Wcat[(k + 0) * 1024 + c0];
        float4 w1 = *(const float4*)&Wcat[(k + 1) * 1024 + c0];
        float4 w2 = *(const float4*)&Wcat[(k + 2) * 1024 + c0];
        float4 w3 = *(const float4*)&Wcat[(k + 3) * 1024 + c0];
#pragma unroll
        for (int ni = 0; ni < 16; ++ni) {
            float4 nv = *(const float4*)&ln[ni * 128 + k];
            acc[ni].x = fmaf(nv.x, w0.x, acc[ni].x);
            acc[ni].y = fmaf(nv.x, w0.y, acc[ni].y);
            acc[ni].z = fmaf(nv.x, w0.z, acc[ni].z);
            acc[ni].w = fmaf(nv.x, w0.w, acc[ni].w);
            acc[ni].x = fmaf(nv.y, w1.x, acc[ni].x);
            acc[ni].y = fmaf(nv.y, w1.y, acc[ni].y);
            acc[ni].z = fmaf(nv.y, w1.z, acc[ni].z);
            acc[ni].w = fmaf(nv.y, w1.w, acc[ni].w);
            acc[ni].x = fmaf(nv.z, w2.x, acc[ni].x);
            acc[ni].y = fmaf(nv.z, w2.y, acc[ni].y);
            acc[ni].z = fmaf(nv.z, w2.z, acc[ni].z);
            acc[ni].w = fmaf(nv.z, w2.w, acc[ni].w);
            acc[ni].x = fmaf(nv.w, w3.x, acc[ni].x);
            acc[ni].y = fmaf(nv.w, w3.y, acc[ni].y);
            acc[ni].z = fmaf(nv.w, w3.z, acc[ni].z);
            acc[ni].w = fmaf(nv.w, w3.w, acc[ni].w);
        }
    }
#pragma unroll
    for (int ni = 0; ni < 16; ++ni) {
        uint2 uu;
        uu.x = pack_bf2(acc[ni].x, acc[ni].y);
        uu.y = pack_bf2(acc[ni].z, acc[ni].w);
        *(uint2*)&P[(n0 + ni) * 512 + t * 2] = uu;
    }
}

// ---------- kernel 4: main — 4 waves/node, hoisted gather pointers ----------
// one block per node, 256 threads = 4 waves; wave w owns h in [w*32, w*32+32)
// No min-waves bound (R4/R5: caps spill), no sched fences (R6: kills overlap).
__global__ __launch_bounds__(256) void main_kernel(
    const float* __restrict__ nodes,
    const float* __restrict__ rbf_che, const int* __restrict__ idx_che,
    const float* __restrict__ rbf_vdw, const int* __restrict__ idx_vdw,
    const unsigned int* __restrict__ P,
    const unsigned short* __restrict__ Bfrag, const float* __restrict__ biasP,
    float* __restrict__ out) {
    // A staging: [b][m][k] bf16, row padded to 40 elems (80 B)
    __shared__ unsigned short sA[2 * 32 * 40];
    __shared__ int sidx[2][MM];
    int n = blockIdx.x;
    int tid = threadIdx.x;
    int w = tid >> 6, l = tid & 63;       // w in {0..3}
    int lhi = l >> 4, llo = l & 15;
    int wold = w >> 1, whalf = w & 1;

    // zero-fill k=20..31 pad (64 rows x 3 uint2)
    if (tid < 192) {
        int row = tid / 3, j = tid - row * 3;
        *(uint2*)&sA[row * 40 + 20 + j * 4] = make_uint2(0u, 0u);
    }
    // vectorized rbf staging: 320 float4s (20 floats = 5 float4 per row)
    for (int i = tid; i < 320; i += 256) {
        int b = (i >= 160) ? 1 : 0, rem = i - b * 160;
        int m = rem / 5, kq = rem - m * 5;
        const float* src = b ? rbf_vdw : rbf_che;
        float4 v = *(const float4*)&src[n * 640 + m * 20 + kq * 4];
        uint2 p;
        p.x = pack_bf2(v.x, v.y);
        p.y = pack_bf2(v.z, v.w);
        *(uint2*)&sA[(b * 32 + m) * 40 + kq * 4] = p;
    }
    if (tid < 64) {
        int b = tid >> 5, m = tid & 31;
        sidx[b][m] = (b ? idx_vdw : idx_che)[n * MM + m];
    }
    __syncthreads();

    float ps0 = 0.f, ps1 = 0.f;   // partial sums for ht=0 / ht=1

#pragma unroll
    for (int b = 0; b < 2; ++b) {
        // A fragments (row = tm*16 + llo, k = lhi*8 + i)
        bf16x8 Af0 = *(const bf16x8*)&sA[(b * 32 + llo) * 40 + lhi * 8];
        bf16x8 Af1 = *(const bf16x8*)&sA[(b * 32 + 16 + llo) * 40 + lhi * 8];
        // neighbor indices for this lane's C/D rows
        int4 vi0 = *(const int4*)&sidx[b][lhi * 4];
        int4 vi1 = *(const int4*)&sidx[b][16 + lhi * 4];

        // hoisted gather base pointers: gp[tm*4+r] -> nbr section, this lane's h base
        int secofs = b * 256 + 128 + w * 32 + llo;
        const unsigned int* gp[8];
        gp[0] = P + (size_t)vi0.x * 512 + secofs;
        gp[1] = P + (size_t)vi0.y * 512 + secofs;
        gp[2] = P + (size_t)vi0.z * 512 + secofs;
        gp[3] = P + (size_t)vi0.w * 512 + secofs;
        gp[4] = P + (size_t)vi1.x * 512 + secofs;
        gp[5] = P + (size_t)vi1.y * 512 + secofs;
        gp[6] = P + (size_t)vi1.z * 512 + secofs;
        gp[7] = P + (size_t)vi1.w * 512 + secofs;

        const unsigned int* sp = P + (size_t)n * 512 + b * 256 + w * 32 + llo;
        const float* bf = biasP + b * 256 + w * 32 + llo;
        const unsigned short* bb = Bfrag + (size_t)((b * 2 + wold) * 8 + whalf * 4) * 512;

#pragma unroll
        for (int ht = 0; ht < 2; ++ht) {
            // B fragments: filt tile (ht*2), core tile (ht*2+1); imm offsets off one base
            bf16x8 Bff = *(const bf16x8*)(bb + ((ht * 2) * 64 + l) * 8);
            bf16x8 Bfc = *(const bf16x8*)(bb + ((ht * 2 + 1) * 64 + l) * 8);

            f32x4 a0f = {0.f, 0.f, 0.f, 0.f}, a0c = {0.f, 0.f, 0.f, 0.f};
            f32x4 a1f = {0.f, 0.f, 0.f, 0.f}, a1c = {0.f, 0.f, 0.f, 0.f};
            a0f = __builtin_amdgcn_mfma_f32_16x16x32_bf16(Af0, Bff, a0f, 0, 0, 0);
            a0c = __builtin_amdgcn_mfma_f32_16x16x32_bf16(Af0, Bfc, a0c, 0, 0, 0);
            a1f = __builtin_amdgcn_mfma_f32_16x16x32_bf16(Af1, Bff, a1f, 0, 0, 0);
            a1c = __builtin_amdgcn_mfma_f32_16x16x32_bf16(Af1, Bfc, a1c, 0, 0, 0);

            unsigned int su = sp[ht * 16];
            float baseF = bf[ht * 16]       + bf_lo(su);
            float baseC = bf[ht * 16 + 128] + bf_hi(su);
            float s = 0.f;
#pragma unroll
            for (int r = 0; r < 4; ++r) {
                unsigned int g = gp[r][ht * 16];   // imm offset 64 B
                float filt = a0f[r] + baseF + bf_lo(g);
                float core = a0c[r] + baseC + bf_hi(g);
                float sg = __builtin_amdgcn_rcpf(1.f + __expf(-filt));
                float sop = softplusf(core);
                s = fmaf(sg, sop, s);
            }
#pragma unroll
            for (int r = 0; r < 4; ++r) {
                unsigned int g = gp[4 + r][ht * 16];
                float filt = a1f[r] + baseF + bf_lo(g);
                float core = a1c[r] + baseC + bf_hi(g);
                float sg = __builtin_amdgcn_rcpf(1.f + __expf(-filt));
                float sop = softplusf(core);
                s = fmaf(sg, sop, s);
            }
            if (ht == 0) ps0 += s;
            else ps1 += s;
        }
    }

    // reduce across the 4 lhi groups (each covered 8 of 32 m-rows)
    float v0 = ps0;
    v0 += __shfl_xor(v0, 16);
    v0 += __shfl_xor(v0, 32);
    float v1 = ps1;
    v1 += __shfl_xor(v1, 16);
    v1 += __shfl_xor(v1, 32);

    if (lhi < 2) {
        int h = w * 32 + lhi * 16 + llo;   // < 128
        float res = lhi ? v1 : v0;
        float x = nodes[n * 128 + h] + res;
        out[n * 128 + h] = softplusf(x);
    }
}

// ---------- launch ----------
extern "C" void kernel_launch(void* const* d_in, const int* in_sizes, int n_in,
                              void* d_out, int out_size, void* d_ws, size_t ws_size,
                              hipStream_t stream) {
    const float* nodes     = (const float*)d_in[0];
    const float* che_rbf   = (const float*)d_in[1];
    const int*   che_idx   = (const int*)d_in[2];
    const float* vdw_rbf   = (const float*)d_in[3];
    const int*   vdw_idx   = (const int*)d_in[4];
    const float* che_Wf    = (const float*)d_in[5];
    const float* che_bf    = (const float*)d_in[6];
    const float* che_Wfull = (const float*)d_in[7];
    const float* che_bfull = (const float*)d_in[8];
    const float* vdw_Wf    = (const float*)d_in[9];
    const float* vdw_bf    = (const float*)d_in[10];
    const float* vdw_Wfull = (const float*)d_in[11];
    const float* vdw_bfull = (const float*)d_in[12];

    char* ws = (char*)d_ws;
    float* Wcat           = (float*)ws;                       // 512 KB
    unsigned short* Bfrag = (unsigned short*)(ws + 524288);   // 32 KB
    float* biasP          = (float*)(ws + 524288 + 32768);    // 2 KB
    unsigned int* P       = (unsigned int*)(ws + 559104);     // 40.96 MB

    build_wcat<<<512, 256, 0, stream>>>(che_Wfull, vdw_Wfull, Wcat);
    build_bfrag<<<8, 256, 0, stream>>>(che_Wf, che_bf, che_Wfull, che_bfull,
                                       vdw_Wf, vdw_bf, vdw_Wfull, vdw_bfull,
                                       Bfrag, biasP);
    proj_kernel<<<NN / 16, 256, 0, stream>>>(nodes, Wcat, P);
    main_kernel<<<NN, 256, 0, stream>>>(nodes, che_rbf, che_idx, vdw_rbf, vdw_idx,
                                        P, Bfrag, biasP, (float*)d_out);
}